// Round 6
// baseline (154.924 us; speedup 1.0000x reference)
//
#include <hip/hip_runtime.h>
#include <hip/hip_bf16.h>

#define S_LEN 2048
#define DHEAD 128

typedef __bf16 bf16x8 __attribute__((ext_vector_type(8)));
typedef float  f32x16 __attribute__((ext_vector_type(16)));

union PK { __bf16 h[2]; unsigned u; };
union BW { unsigned w4[4]; bf16x8 v; };
union F4 { float4 v; float f[4]; };

struct TrueT  { static constexpr bool value = true;  };
struct FalseT { static constexpr bool value = false; };

__device__ __forceinline__ bf16x8 cvt8(float4 a, float4 b) {
  bf16x8 r;
  r[0] = (__bf16)a.x; r[1] = (__bf16)a.y; r[2] = (__bf16)a.z; r[3] = (__bf16)a.w;
  r[4] = (__bf16)b.x; r[5] = (__bf16)b.y; r[6] = (__bf16)b.z; r[7] = (__bf16)b.w;
  return r;
}

// Flash attention fwd, causal. Block = 4 waves, 32 q rows, 4-way kv-parity
// split over 128-key shared LDS tiles; merged at end.
// ALL global loads coalesced (8 cache lines / instruction).
// S^T = mfma(K,Q) 32x32x16 -> in-register softmax; O^T = mfma(V^T, P^T).
// Raw barriers (no vmcnt drain); K/V(i+1) reg-prefetched across compute.
__global__ __launch_bounds__(256, 2) void attn_fwd(
    const float* __restrict__ Q, const float* __restrict__ K,
    const float* __restrict__ V, float* __restrict__ Out) {
  // [0,32768): K bf16 [128 kv][256B], 16B-slot swz ^((kv&15)<<4)
  // [32768,65536): V^T bf16 [128 d][256B], 16B-slot swz ^(vkey(d)<<4),
  //                vkey(d) = (d&15) ^ ((d>>2)&7)
  // prologue overlay: Q fp32 stage [32][512B] @0
  // epilogue overlay: Ob0@0 (32x132 f32), Ob1@16896, ml@36864, Lbuf@37888
  __shared__ __align__(16) char lds[65536];
  char* Kl = lds;
  char* Vl = lds + 32768;

  const int tid  = threadIdx.x;
  const int w    = tid >> 6;
  const int lane = tid & 63;
  const int h    = lane >> 5;
  const int lq   = lane & 31;

  const int bi    = blockIdx.x;
  const int batch = bi & 7;                                      // XCD L2 locality
  const int T     = (bi < 256) ? (63 - (bi >> 3)) : ((bi - 256) >> 3);  // long+short pair
  const int q0    = T << 5;
  const int q     = q0 + lq;

  const float* Qb = Q + (size_t)batch * S_LEN * DHEAD;
  const float* Kb = K + (size_t)batch * S_LEN * DHEAD;
  const float* Vb = V + (size_t)batch * S_LEN * DHEAD;

  // ---- staging maps ----
  const int srow = tid >> 5;        // K: rows srow+8j (2 rows/instr/wave)
  const int scol = tid & 31;        // K: floats scol*4..+3
  const int vu   = lane >> 3;       // V: pair set
  const int vv   = lane & 7;        // V: d-chunk set

  float4 kreg[16];                  // K tile prefetch
  F4     vreg[16];                  // V prefetch: [p*8 + rb*4 + c]

  auto issueKA = [&](int kb) {
#pragma unroll
    for (int j = 0; j < 8; ++j)
      kreg[j] = *(const float4*)(Kb + (size_t)(kb + srow + 8 * j) * DHEAD + scol * 4);
  };
  auto issueKB = [&](int kb) {
#pragma unroll
    for (int j = 8; j < 16; ++j)
      kreg[j] = *(const float4*)(Kb + (size_t)(kb + srow + 8 * j) * DHEAD + scol * 4);
  };
  // V: thread owns pairs a = 16w+vu (+8), rows 2a,2a+1, d floats 4vv+32c..+3.
  // Per instruction: 8 rows x contiguous 128B = 8 lines (coalesced).
  auto vload = [&](int kb, int c) {
#pragma unroll
    for (int p = 0; p < 2; ++p) {
      const int a = 16 * w + vu + 8 * p;
#pragma unroll
      for (int rb = 0; rb < 2; ++rb)
        vreg[p * 8 + rb * 4 + c].v =
            *(const float4*)(Vb + (size_t)(kb + 2 * a + rb) * DHEAD + 4 * vv + 32 * c);
    }
  };
  auto issueVA = [&](int kb) { vload(kb, 0); vload(kb, 1); };
  auto issueVB = [&](int kb) { vload(kb, 2); vload(kb, 3); };

  auto writeK = [&]() {
#pragma unroll
    for (int j = 0; j < 16; ++j) {
      const int row = srow + 8 * j;
      PK p0, p1;
      p0.h[0] = (__bf16)kreg[j].x; p0.h[1] = (__bf16)kreg[j].y;
      p1.h[0] = (__bf16)kreg[j].z; p1.h[1] = (__bf16)kreg[j].w;
      *(uint2*)(Kl + row * 256 + ((scol * 8) ^ ((row & 15) << 4))) = make_uint2(p0.u, p1.u);
    }
  };
  auto writeV = [&]() {
#pragma unroll
    for (int p = 0; p < 2; ++p) {
      const int a = 16 * w + vu + 8 * p;
#pragma unroll
      for (int c = 0; c < 4; ++c)
#pragma unroll
        for (int e = 0; e < 4; ++e) {
          const int d = 4 * vv + 32 * c + e;
          PK pk;
          pk.h[0] = (__bf16)vreg[p * 8 + 0 + c].f[e];   // kv = 2a
          pk.h[1] = (__bf16)vreg[p * 8 + 4 + c].f[e];   // kv = 2a+1
          const int vkey = (d & 15) ^ ((d >> 2) & 7);
          *(unsigned*)(Vl + d * 256 + ((4 * a) ^ (vkey << 4))) = pk.u;
        }
    }
  };

  // ---- Q fragments via coalesced LDS stage ----
  const float scale = 0.08838834764831845f;
  bf16x8 qf[8];
  {
    const int qr = tid >> 3;       // 0..31
    const int qc = tid & 7;        // 0..7
    float4 qt[4];
#pragma unroll
    for (int c = 0; c < 4; ++c)
      qt[c] = *(const float4*)(Qb + (size_t)(q0 + qr) * DHEAD + 16 * qc + 4 * c);
    issueKA(0); issueKB(0); issueVA(0); issueVB(0);   // tile 0 in flight
#pragma unroll
    for (int c = 0; c < 4; ++c)
      *(float4*)(Kl + qr * 512 + ((64 * qc + 16 * c) ^ ((qr & 7) << 4))) = qt[c];
    __syncthreads();
#pragma unroll
    for (int ks = 0; ks < 8; ++ks) {
      const int x = 64 * ks + 32 * h;
      float4 a = *(const float4*)(Kl + lq * 512 + (x ^ ((lq & 7) << 4)));
      float4 b = *(const float4*)(Kl + lq * 512 + ((x + 16) ^ ((lq & 7) << 4)));
      a.x *= scale; a.y *= scale; a.z *= scale; a.w *= scale;
      b.x *= scale; b.y *= scale; b.z *= scale; b.w *= scale;
      qf[ks] = cvt8(a, b);
    }
    __syncthreads();   // Q stage region (Kl) free for K tiles
  }

  float  mrun = -INFINITY, lrun = 0.f;
  f32x16 ob[4];
#pragma unroll
  for (int db = 0; db < 4; ++db)
#pragma unroll
    for (int r = 0; r < 16; ++r) ob[db][r] = 0.f;

  const int kvo   = 32 * w;                              // wave's kv window offset
  const int swk   = (lq & 15) << 4;                      // K read swizzle
  const int vkey4 = ((lq & 15) ^ ((lq >> 2) & 7)) << 4;  // V read swizzle

  auto tile = [&](int kb, auto diagc) {
    constexpr bool DIAG = decltype(diagc)::value;
    const int rb = (kvo + lq) * 256;

    // ---- S^T = K * Q^T ----
    f32x16 sa, sb;
#pragma unroll
    for (int r = 0; r < 16; ++r) { sa[r] = 0.f; sb[r] = 0.f; }
    __builtin_amdgcn_s_setprio(1);
#pragma unroll
    for (int ks = 0; ks < 4; ++ks) {
      bf16x8 kf = *(const bf16x8*)(Kl + rb + ((32 * ks + 16 * h) ^ swk));
      sa = __builtin_amdgcn_mfma_f32_32x32x16_bf16(kf, qf[ks], sa, 0, 0, 0);
    }
#pragma unroll
    for (int ks = 4; ks < 8; ++ks) {
      bf16x8 kf = *(const bf16x8*)(Kl + rb + ((32 * ks + 16 * h) ^ swk));
      sb = __builtin_amdgcn_mfma_f32_32x32x16_bf16(kf, qf[ks], sb, 0, 0, 0);
    }
    __builtin_amdgcn_s_setprio(0);
    f32x16 sv;
#pragma unroll
    for (int r = 0; r < 16; ++r) sv[r] = sa[r] + sb[r];

    // ---- in-register softmax (lane owns P column of row q) ----
    bool ok[16];
    if constexpr (DIAG) {
#pragma unroll
      for (int r = 0; r < 16; ++r) {
        const int kvr = kb + (r & 3) + 8 * (r >> 2) + 4 * h;
        ok[r] = (kvr <= q);
        sv[r] = ok[r] ? sv[r] : -INFINITY;
      }
    }
    float mx = sv[0];
#pragma unroll
    for (int r = 1; r < 16; ++r) mx = fmaxf(mx, sv[r]);
    mx = fmaxf(mx, __shfl_xor(mx, 32));

    float mnew = mrun;                       // T13 defer-max
    if (__any(mx > mrun + 8.f)) {
      mnew = fmaxf(mrun, mx);
      const float alpha = __expf(mrun - mnew);
      lrun *= alpha;
#pragma unroll
      for (int db = 0; db < 4; ++db)
#pragma unroll
        for (int r = 0; r < 16; ++r) ob[db][r] *= alpha;
      mrun = mnew;
    }

    float pv[16];
    float rsum = 0.f;
#pragma unroll
    for (int r = 0; r < 16; ++r) {
      float e = __expf(sv[r] - mnew);
      if constexpr (DIAG) e = ok[r] ? e : 0.f;
      pv[r] = e;
      rsum += e;
    }
    rsum += __shfl_xor(rsum, 32);
    lrun += rsum;

    // ---- P -> bf16 packs + half-wave exchange (T12) ----
    unsigned c[8];
#pragma unroll
    for (int i = 0; i < 8; ++i) {
      PK pk;
      pk.h[0] = (__bf16)pv[2 * i];
      pk.h[1] = (__bf16)pv[2 * i + 1];
      c[i] = pk.u;
    }
    const unsigned e0 = (unsigned)__shfl_xor((int)(h ? c[0] : c[2]), 32);
    const unsigned e1 = (unsigned)__shfl_xor((int)(h ? c[1] : c[3]), 32);
    const unsigned e2 = (unsigned)__shfl_xor((int)(h ? c[4] : c[6]), 32);
    const unsigned e3 = (unsigned)__shfl_xor((int)(h ? c[5] : c[7]), 32);
    BW pb0, pb1;
    pb0.w4[0] = h ? e0   : c[0];
    pb0.w4[1] = h ? e1   : c[1];
    pb0.w4[2] = h ? c[2] : e0;
    pb0.w4[3] = h ? c[3] : e1;
    pb1.w4[0] = h ? e2   : c[4];
    pb1.w4[1] = h ? e3   : c[5];
    pb1.w4[2] = h ? c[6] : e2;
    pb1.w4[3] = h ? c[7] : e3;

    // ---- PV: O^T += V^T * P^T ----
    __builtin_amdgcn_s_setprio(1);
#pragma unroll
    for (int db = 0; db < 4; ++db) {
      const char* vp = Vl + (32 * db + lq) * 256;
      bf16x8 a0 = *(const bf16x8*)(vp + ((2 * kvo + 16 * h) ^ vkey4));
      ob[db] = __builtin_amdgcn_mfma_f32_32x32x16_bf16(a0, pb0.v, ob[db], 0, 0, 0);
      bf16x8 a1 = *(const bf16x8*)(vp + ((2 * kvo + 32 + 16 * h) ^ vkey4));
      ob[db] = __builtin_amdgcn_mfma_f32_32x32x16_bf16(a1, pb1.v, ob[db], 0, 0, 0);
    }
    __builtin_amdgcn_s_setprio(0);
  };

  // ---- main pipelined loop ----
  const int nit = (q0 + 159) >> 7;   // ceil((q0+32)/128)
  for (int i = 0; i < nit; ++i) {
    if (i) __builtin_amdgcn_s_barrier();          // LDS free (no vmcnt drain)
    __builtin_amdgcn_sched_barrier(0);
    writeK();                                      // waits vmcnt on kreg
    writeV();                                      // waits vmcnt on vreg
    asm volatile("s_waitcnt lgkmcnt(0)" ::: "memory");
    __builtin_amdgcn_s_barrier();                  // tile ready (no vmcnt drain)
    __builtin_amdgcn_sched_barrier(0);
    const bool more = (i + 1 < nit);
    if (more) { issueKA((i + 1) << 7); issueVA((i + 1) << 7); }  // fly across compute
    const int kb = (i << 7) + kvo;
    if (kb <= q0) {
      if (kb == q0) tile(kb, TrueT{});
      else          tile(kb, FalseT{});
    }
    if (more) { issueKB((i + 1) << 7); issueVB((i + 1) << 7); }  // land during writeK/A
  }

  // ================= merge 4 kv-parity partials =================
  __syncthreads();
  float2* ml   = (float2*)(lds + 36864);
  float*  Lbuf = (float*)(lds + 37888);
  float*  Ob0  = (float*)(lds);
  float*  Ob1  = (float*)(lds + 16896);

  if (h == 0) ml[w * 32 + lq] = make_float2(mrun, lrun);
  __syncthreads();

  float M = -INFINITY;
#pragma unroll
  for (int ww = 0; ww < 4; ++ww) M = fmaxf(M, ml[ww * 32 + lq].x);
  float L = 0.f;
#pragma unroll
  for (int ww = 0; ww < 4; ++ww) {
    float2 v = ml[ww * 32 + lq];
    L += v.y * __expf(v.x - M);
  }
  const float fw = __expf(mrun - M);   // 0 for idle waves (mrun = -inf)
  if (w == 0 && h == 0) Lbuf[lq] = 1.f / L;

  float* Ob = (w & 1) ? Ob1 : Ob0;
  if (w < 2) {
#pragma unroll
    for (int db = 0; db < 4; ++db)
#pragma unroll
      for (int rr = 0; rr < 4; ++rr) {
        float4 val = { ob[db][4 * rr + 0] * fw, ob[db][4 * rr + 1] * fw,
                       ob[db][4 * rr + 2] * fw, ob[db][4 * rr + 3] * fw };
        *(float4*)(Ob + lq * 132 + 32 * db + 8 * rr + 4 * h) = val;
      }
  }
  __syncthreads();
  if (w >= 2) {
#pragma unroll
    for (int db = 0; db < 4; ++db)
#pragma unroll
      for (int rr = 0; rr < 4; ++rr) {
        float* p = Ob + lq * 132 + 32 * db + 8 * rr + 4 * h;
        float4 cur = *(float4*)p;
        cur.x += ob[db][4 * rr + 0] * fw;
        cur.y += ob[db][4 * rr + 1] * fw;
        cur.z += ob[db][4 * rr + 2] * fw;
        cur.w += ob[db][4 * rr + 3] * fw;
        *(float4*)p = cur;
      }
  }
  __syncthreads();

  // ---- cooperative coalesced store ----
  const int row = tid >> 3;
  const int d0  = (tid & 7) * 16;
  const float inv = Lbuf[row];
  float* orow = Out + ((size_t)(batch * S_LEN + q0 + row)) * DHEAD + d0;
#pragma unroll
  for (int j = 0; j < 4; ++j) {
    float4 a = *(float4*)(Ob0 + row * 132 + d0 + 4 * j);
    float4 b = *(float4*)(Ob1 + row * 132 + d0 + 4 * j);
    float4 o = { (a.x + b.x) * inv, (a.y + b.y) * inv,
                 (a.z + b.z) * inv, (a.w + b.w) * inv };
    *(float4*)(orow + 4 * j) = o;
  }
}

extern "C" void kernel_launch(void* const* d_in, const int* in_sizes, int n_in,
                              void* d_out, int out_size, void* d_ws, size_t ws_size,
                              hipStream_t stream) {
  const float* q = (const float*)d_in[0];
  const float* k = (const float*)d_in[1];
  const float* v = (const float*)d_in[2];
  float* out = (float*)d_out;
  const int B = in_sizes[0] / (S_LEN * DHEAD);
  dim3 grid(B * (S_LEN / 32));
  attn_fwd<<<grid, dim3(256), 0, stream>>>(q, k, v, out);
}

// Round 7
// 45.461 us; speedup vs baseline: 3.4079x; 3.4079x over previous
//
#include <hip/hip_runtime.h>
#include <hip/hip_bf16.h>

#define S_LEN 2048
#define DHEAD 128

typedef __bf16 bf16x8 __attribute__((ext_vector_type(8)));
typedef float  f32x16 __attribute__((ext_vector_type(16)));

union PK { __bf16 h[2]; unsigned u; };
union BW { unsigned w4[4]; bf16x8 v; };

#define AS1C(p) ((const __attribute__((address_space(1))) void*)(p))
#define AS3(p)  ((__attribute__((address_space(3))) void*)(p))

struct TrueT  { static constexpr bool value = true;  };
struct FalseT { static constexpr bool value = false; };

__device__ __forceinline__ bf16x8 cvt8(float4 a, float4 b) {
  bf16x8 r;
  r[0] = (__bf16)a.x; r[1] = (__bf16)a.y; r[2] = (__bf16)a.z; r[3] = (__bf16)a.w;
  r[4] = (__bf16)b.x; r[5] = (__bf16)b.y; r[6] = (__bf16)b.z; r[7] = (__bf16)b.w;
  return r;
}

// ---------------- prepass: K fp32 -> bf16, 16B-chunk swizzled within 256B rows ----
// stored slot of logical d-chunk c (row kv) = c ^ (kv & 15)
__global__ __launch_bounds__(256) void kprep(const float* __restrict__ K,
                                             char* __restrict__ Kb) {
  const int idx = blockIdx.x * 256 + threadIdx.x;
  const int c  = idx & 15;
  const int kv = (idx >> 4) & (S_LEN - 1);
  const int b  = idx >> 15;
  const float4* src = (const float4*)(K + ((size_t)(b * S_LEN + kv) * DHEAD + c * 8));
  bf16x8 v = cvt8(src[0], src[1]);
  *(bf16x8*)(Kb + (size_t)(b * S_LEN + kv) * 256 + ((c ^ (kv & 15)) << 4)) = v;
}

// ---------------- prepass: V fp32 -> V^T bf16 [b][d][kv], swizzled per 256B group --
// stored slot of logical kv-chunk within its 16-chunk group (row d) = chunk ^ (d & 15)
__global__ __launch_bounds__(256) void vprep(const float* __restrict__ V,
                                             char* __restrict__ Vt) {
  __shared__ float t[256 * 33];
  const int tid = threadIdx.x;
  const int b   = blockIdx.x >> 5;
  const int kv0 = ((blockIdx.x >> 2) & 7) << 8;   // 256-kv tile
  const int d0  = (blockIdx.x & 3) << 5;          // 32-d tile
#pragma unroll
  for (int p = 0; p < 8; ++p) {
    const int f = p * 256 + tid;
    const int row = f >> 3, c4 = f & 7;
    float4 v = *(const float4*)(V + ((size_t)(b * S_LEN + kv0 + row) * DHEAD + d0 + c4 * 4));
    float* dst = t + row * 33 + c4 * 4;
    dst[0] = v.x; dst[1] = v.y; dst[2] = v.z; dst[3] = v.w;
  }
  __syncthreads();
#pragma unroll
  for (int p = 0; p < 4; ++p) {
    const int dl  = 8 * p + (tid >> 5);
    const int kvc = tid & 31;
    const int d   = d0 + dl;
    bf16x8 v;
#pragma unroll
    for (int j = 0; j < 8; ++j) v[j] = (__bf16)t[(8 * kvc + j) * 33 + dl];
    const int slot = ((kvc & 15) ^ (d & 15)) | (kvc & 16);
    *(bf16x8*)(Vt + (size_t)(b * DHEAD + d) * (S_LEN * 2) + kv0 * 2 + (slot << 4)) = v;
  }
}

// ---------------- main: flash attention fwd, causal ------------------------------
// 4 waves, 32 q rows/block, 128-key LDS tiles, 4-way kv split, merge at end.
// Staging = global_load_lds (zero registers); 3-barrier counted-vmcnt pipeline:
//   [vmcnt(8): K ready] Ba -> QK^T+softmax (V in flight) -> [vmcnt(0)] Bb ->
//   issue K(i+1) -> PV -> Bc -> issue V(i+1)
__global__ __launch_bounds__(256, 2) void attn_fwd(
    const float* __restrict__ Q, const char* __restrict__ Kb,
    const char* __restrict__ Vt, float* __restrict__ Out) {
  // [0,32768): K bf16 [128 kv][256B]  (swizzle baked into global layout)
  // [32768,65536): V^T bf16 [128 d][256B]
  // epilogue overlay: Ob0@0 (32x132 f32), Ob1@16896, ml@36864, Lbuf@37888
  __shared__ __align__(16) char lds[65536];
  char* Kl = lds;
  char* Vl = lds + 32768;

  const int tid  = threadIdx.x;
  const int w    = tid >> 6;
  const int lane = tid & 63;
  const int h    = lane >> 5;
  const int lq   = lane & 31;

  const int bi    = blockIdx.x;
  const int batch = bi & 7;                                            // XCD L2 locality
  const int T     = (bi < 256) ? (63 - (bi >> 3)) : ((bi - 256) >> 3); // long+short pair
  const int q0    = T << 5;
  const int q     = q0 + lq;

  const float* Qb  = Q  + (size_t)batch * S_LEN * DHEAD;
  const char*  Kbb = Kb + (size_t)batch * S_LEN * 256;
  const char*  Vtb = Vt + (size_t)batch * DHEAD * (S_LEN * 2);

  // ---- Q fragments (fp32 direct one-time load, pre-scaled) ----
  const float scale = 0.08838834764831845f;
  bf16x8 qf[8];
  {
    const float* qp = Qb + (size_t)q * DHEAD + 8 * h;
#pragma unroll
    for (int ks = 0; ks < 8; ++ks) {
      float4 a = *(const float4*)(qp + 16 * ks);
      float4 b = *(const float4*)(qp + 16 * ks + 4);
      a.x *= scale; a.y *= scale; a.z *= scale; a.w *= scale;
      b.x *= scale; b.y *= scale; b.z *= scale; b.w *= scale;
      qf[ks] = cvt8(a, b);
    }
  }
  __builtin_amdgcn_sched_barrier(0);  // Q loads fully drained before any gll issue

  // ---- async staging: 8 global_load_lds per wave per tile, zero registers ----
  auto issueK = [&](int kv0) {
    const char* src = Kbb + (size_t)kv0 * 256 + (w * 8) * 1024 + lane * 16;
    char* dst = Kl + (w * 8) * 1024;   // + lane*16 implicit in HW
#pragma unroll
    for (int j = 0; j < 8; ++j)
      __builtin_amdgcn_global_load_lds(AS1C(src + j * 1024), AS3(dst + j * 1024), 16, 0, 0);
  };
  auto issueV = [&](int kv0) {
    const int dl = lane >> 4;
    const int cs = (lane & 15) << 4;
#pragma unroll
    for (int j = 0; j < 8; ++j) {
      const int c = w * 8 + j;   // chunk c = d rows 4c..4c+3
      __builtin_amdgcn_global_load_lds(
          AS1C(Vtb + (size_t)(4 * c + dl) * (S_LEN * 2) + kv0 * 2 + cs),
          AS3(Vl + c * 1024), 16, 0, 0);
    }
  };

  float  mrun = -INFINITY, lrun = 0.f;
  f32x16 ob[4];
#pragma unroll
  for (int db = 0; db < 4; ++db)
#pragma unroll
    for (int r = 0; r < 16; ++r) ob[db][r] = 0.f;

  const int kvo = 32 * w;
  const int swz = (lq & 15) << 4;

  const int nit = (q0 + 159) >> 7;   // ceil((q0+32)/128)
  issueK(0);
  issueV(0);

  for (int i = 0; i < nit; ++i) {
    asm volatile("s_waitcnt vmcnt(8)" ::: "memory");   // K(i) landed (V still flying)
    __builtin_amdgcn_s_barrier();                      // Ba: K ready for all waves
    __builtin_amdgcn_sched_barrier(0);

    const int  kb   = (i << 7) + kvo;
    const bool act  = (kb <= q0);
    const bool diag = (kb == q0);

    f32x16 sv;
    float  pv[16];
    BW pb0, pb1;

    if (act) {
      // ---- S^T = K * Q^T ----
      f32x16 sa, sb;
#pragma unroll
      for (int r = 0; r < 16; ++r) { sa[r] = 0.f; sb[r] = 0.f; }
      __builtin_amdgcn_s_setprio(1);
      const int rb = (kvo + lq) * 256;
#pragma unroll
      for (int ks = 0; ks < 4; ++ks) {
        bf16x8 kf = *(const bf16x8*)(Kl + rb + ((32 * ks + 16 * h) ^ swz));
        sa = __builtin_amdgcn_mfma_f32_32x32x16_bf16(kf, qf[ks], sa, 0, 0, 0);
      }
#pragma unroll
      for (int ks = 4; ks < 8; ++ks) {
        bf16x8 kf = *(const bf16x8*)(Kl + rb + ((32 * ks + 16 * h) ^ swz));
        sb = __builtin_amdgcn_mfma_f32_32x32x16_bf16(kf, qf[ks], sb, 0, 0, 0);
      }
      __builtin_amdgcn_s_setprio(0);
#pragma unroll
      for (int r = 0; r < 16; ++r) sv[r] = sa[r] + sb[r];

      // ---- in-register softmax ----
      bool ok[16];
      if (diag) {
#pragma unroll
        for (int r = 0; r < 16; ++r) {
          const int kvr = kb + (r & 3) + 8 * (r >> 2) + 4 * h;
          ok[r] = (kvr <= q);
          sv[r] = ok[r] ? sv[r] : -INFINITY;
        }
      }
      float mx = sv[0];
#pragma unroll
      for (int r = 1; r < 16; ++r) mx = fmaxf(mx, sv[r]);
      mx = fmaxf(mx, __shfl_xor(mx, 32));

      float mnew = mrun;                       // T13 defer-max
      if (__any(mx > mrun + 8.f)) {
        mnew = fmaxf(mrun, mx);
        const float alpha = __expf(mrun - mnew);
        lrun *= alpha;
#pragma unroll
        for (int db = 0; db < 4; ++db)
#pragma unroll
          for (int r = 0; r < 16; ++r) ob[db][r] *= alpha;
        mrun = mnew;
      }

      float rsum = 0.f;
#pragma unroll
      for (int r = 0; r < 16; ++r) {
        float e = __expf(sv[r] - mnew);
        if (diag) e = ok[r] ? e : 0.f;
        pv[r] = e;
        rsum += e;
      }
      rsum += __shfl_xor(rsum, 32);
      lrun += rsum;

      // ---- P -> bf16 packs + half-wave exchange (T12) ----
      unsigned c[8];
#pragma unroll
      for (int ii = 0; ii < 8; ++ii) {
        PK pk;
        pk.h[0] = (__bf16)pv[2 * ii];
        pk.h[1] = (__bf16)pv[2 * ii + 1];
        c[ii] = pk.u;
      }
      const unsigned e0 = (unsigned)__shfl_xor((int)(h ? c[0] : c[2]), 32);
      const unsigned e1 = (unsigned)__shfl_xor((int)(h ? c[1] : c[3]), 32);
      const unsigned e2 = (unsigned)__shfl_xor((int)(h ? c[4] : c[6]), 32);
      const unsigned e3 = (unsigned)__shfl_xor((int)(h ? c[5] : c[7]), 32);
      pb0.w4[0] = h ? e0   : c[0];
      pb0.w4[1] = h ? e1   : c[1];
      pb0.w4[2] = h ? c[2] : e0;
      pb0.w4[3] = h ? c[3] : e1;
      pb1.w4[0] = h ? e2   : c[4];
      pb1.w4[1] = h ? e3   : c[5];
      pb1.w4[2] = h ? c[6] : e2;
      pb1.w4[3] = h ? c[7] : e3;
    }

    asm volatile("s_waitcnt vmcnt(0)" ::: "memory");   // V(i) landed
    __builtin_amdgcn_s_barrier();                      // Bb: all QK^T reads done
    __builtin_amdgcn_sched_barrier(0);

    if (i + 1 < nit) issueK((i + 1) << 7);             // K region free; fly under PV

    if (act) {
      // ---- PV: O^T += V^T * P^T ----
      __builtin_amdgcn_s_setprio(1);
#pragma unroll
      for (int db = 0; db < 4; ++db) {
        const char* vp = Vl + (32 * db + lq) * 256;
        bf16x8 a0 = *(const bf16x8*)(vp + ((64 * w + 16 * h) ^ swz));
        ob[db] = __builtin_amdgcn_mfma_f32_32x32x16_bf16(a0, pb0.v, ob[db], 0, 0, 0);
        bf16x8 a1 = *(const bf16x8*)(vp + ((64 * w + 32 + 16 * h) ^ swz));
        ob[db] = __builtin_amdgcn_mfma_f32_32x32x16_bf16(a1, pb1.v, ob[db], 0, 0, 0);
      }
      __builtin_amdgcn_s_setprio(0);
    }

    __builtin_amdgcn_s_barrier();                      // Bc: all PV reads done
    __builtin_amdgcn_sched_barrier(0);
    if (i + 1 < nit) issueV((i + 1) << 7);             // V region free
  }

  // ================= merge 4 kv-parity partials =================
  __syncthreads();
  float2* ml   = (float2*)(lds + 36864);
  float*  Lbuf = (float*)(lds + 37888);
  float*  Ob0  = (float*)(lds);
  float*  Ob1  = (float*)(lds + 16896);

  if (h == 0) ml[w * 32 + lq] = make_float2(mrun, lrun);
  __syncthreads();

  float M = -INFINITY;
#pragma unroll
  for (int ww = 0; ww < 4; ++ww) M = fmaxf(M, ml[ww * 32 + lq].x);
  float L = 0.f;
#pragma unroll
  for (int ww = 0; ww < 4; ++ww) {
    float2 v = ml[ww * 32 + lq];
    L += v.y * __expf(v.x - M);
  }
  const float fw = __expf(mrun - M);   // 0 for idle waves (mrun = -inf)
  if (w == 0 && h == 0) Lbuf[lq] = 1.f / L;

  float* Ob = (w & 1) ? Ob1 : Ob0;
  if (w < 2) {
#pragma unroll
    for (int db = 0; db < 4; ++db)
#pragma unroll
      for (int rr = 0; rr < 4; ++rr) {
        float4 val = { ob[db][4 * rr + 0] * fw, ob[db][4 * rr + 1] * fw,
                       ob[db][4 * rr + 2] * fw, ob[db][4 * rr + 3] * fw };
        *(float4*)(Ob + lq * 132 + 32 * db + 8 * rr + 4 * h) = val;
      }
  }
  __syncthreads();
  if (w >= 2) {
#pragma unroll
    for (int db = 0; db < 4; ++db)
#pragma unroll
      for (int rr = 0; rr < 4; ++rr) {
        float* p = Ob + lq * 132 + 32 * db + 8 * rr + 4 * h;
        float4 cur = *(float4*)p;
        cur.x += ob[db][4 * rr + 0] * fw;
        cur.y += ob[db][4 * rr + 1] * fw;
        cur.z += ob[db][4 * rr + 2] * fw;
        cur.w += ob[db][4 * rr + 3] * fw;
        *(float4*)p = cur;
      }
  }
  __syncthreads();

  // ---- cooperative coalesced store ----
  const int row = tid >> 3;
  const int d0  = (tid & 7) * 16;
  const float inv = Lbuf[row];
  float* orow = Out + ((size_t)(batch * S_LEN + q0 + row)) * DHEAD + d0;
#pragma unroll
  for (int j = 0; j < 4; ++j) {
    float4 a = *(float4*)(Ob0 + row * 132 + d0 + 4 * j);
    float4 b = *(float4*)(Ob1 + row * 132 + d0 + 4 * j);
    float4 o = { (a.x + b.x) * inv, (a.y + b.y) * inv,
                 (a.z + b.z) * inv, (a.w + b.w) * inv };
    *(float4*)(orow + 4 * j) = o;
  }
}

extern "C" void kernel_launch(void* const* d_in, const int* in_sizes, int n_in,
                              void* d_out, int out_size, void* d_ws, size_t ws_size,
                              hipStream_t stream) {
  const float* q = (const float*)d_in[0];
  const float* k = (const float*)d_in[1];
  const float* v = (const float*)d_in[2];
  float* out = (float*)d_out;
  const int B = in_sizes[0] / (S_LEN * DHEAD);   // 8

  char* kb = (char*)d_ws;                                   // B*2048*256  = 4 MB
  char* vt = (char*)d_ws + (size_t)B * S_LEN * 256;         // B*128*4096  = 4 MB

  kprep<<<dim3(B * 128), dim3(256), 0, stream>>>(k, kb);
  vprep<<<dim3(B * 32),  dim3(256), 0, stream>>>(v, vt);
  attn_fwd<<<dim3(B * (S_LEN / 32)), dim3(256), 0, stream>>>(q, kb, vt, out);
}

// Round 9
// 35.638 us; speedup vs baseline: 4.3471x; 1.2756x over previous
//
#include <hip/hip_runtime.h>
#include <hip/hip_bf16.h>

#define S_LEN 2048
#define DHEAD 128

typedef __bf16 bf16x8 __attribute__((ext_vector_type(8)));
typedef float  f32x16 __attribute__((ext_vector_type(16)));

union PK { __bf16 h[2]; unsigned u; };
union BW { unsigned w4[4]; bf16x8 v; };

__device__ __forceinline__ bf16x8 cvt8(float4 a, float4 b) {
  bf16x8 r;
  r[0] = (__bf16)a.x; r[1] = (__bf16)a.y; r[2] = (__bf16)a.z; r[3] = (__bf16)a.w;
  r[4] = (__bf16)b.x; r[5] = (__bf16)b.y; r[6] = (__bf16)b.z; r[7] = (__bf16)b.w;
  return r;
}

// permlane32_swap semantics: a' = {lane<32: a, lane>=32: b[lane-32]},
//                            b' = {lane<32: a[lane+32], lane>=32: b}
#if __has_builtin(__builtin_amdgcn_permlane32_swap)
__device__ __forceinline__ void plswap(unsigned &a, unsigned &b) {
  auto r = __builtin_amdgcn_permlane32_swap((int)a, (int)b, false, false);
  a = (unsigned)r[0];
  b = (unsigned)r[1];
}
#else
__device__ __forceinline__ void plswap(unsigned &a, unsigned &b) {
  const bool hi = (threadIdx.x & 32) != 0;
  const unsigned ea = (unsigned)__shfl_xor((int)a, 32);
  const unsigned eb = (unsigned)__shfl_xor((int)b, 32);
  const unsigned na = hi ? eb : a;
  const unsigned nb = hi ? b : ea;
  a = na; b = nb;
}
#endif

// -------- prepass K: fp32 [b][kv][d] -> fragment-ordered bf16 --------
// Kp chunk(b, t, ks, h, lq)[j] = K[b][32t+lq][16ks+8h+j], 16B chunks,
// byte = (b*64+t)*8192 + ks*1024 + h*512 + lq*16.
// Main-kernel fragment load (fixed ks,h): lanes -> contiguous 1KB.
__global__ __launch_bounds__(256) void kprep(const float* __restrict__ K,
                                             char* __restrict__ Kp) {
  const int tid = threadIdx.x;
  const int b = blockIdx.x >> 6;
  const int t = blockIdx.x & 63;
  const int row = tid >> 3;   // lq
  const int c8  = tid & 7;    // ks
  const float4* src = (const float4*)(K + ((size_t)(b * S_LEN + 32 * t + row) * DHEAD + 16 * c8));
  float4 f0 = src[0], f1 = src[1], f2 = src[2], f3 = src[3];
  char* dst = Kp + (size_t)(b * 64 + t) * 8192 + c8 * 1024 + row * 16;
  *(bf16x8*)(dst)       = cvt8(f0, f1);   // h=0
  *(bf16x8*)(dst + 512) = cvt8(f2, f3);   // h=1
}

// -------- prepass V: fp32 [b][kv][d] -> transposed fragment-ordered bf16 ----
// Vp chunk(b, u, db, s, h, lq)[j] = V[b][32u+16s+8h+j][32db+lq],
// byte = (b*64+u)*8192 + (db*2+s)*1024 + h*512 + lq*16.
__global__ __launch_bounds__(256) void vprep(const float* __restrict__ V,
                                             char* __restrict__ Vp) {
  __shared__ float t[32 * 132];
  const int tid = threadIdx.x;
  const int b = blockIdx.x >> 6;
  const int u = blockIdx.x & 63;
  const int row = tid >> 3;
  const int c8  = tid & 7;
  const float4* src = (const float4*)(V + ((size_t)(b * S_LEN + 32 * u + row) * DHEAD + 16 * c8));
  float4 f0 = src[0], f1 = src[1], f2 = src[2], f3 = src[3];
  float* d = t + row * 132 + 16 * c8;
  *(float4*)(d) = f0; *(float4*)(d + 4) = f1;
  *(float4*)(d + 8) = f2; *(float4*)(d + 12) = f3;
  __syncthreads();
#pragma unroll
  for (int k = 0; k < 2; ++k) {
    const int id = tid * 2 + k;
    const int lq = id & 31, hh = (id >> 5) & 1, s = (id >> 6) & 1, db = (id >> 7) & 3;
    bf16x8 o;
#pragma unroll
    for (int j = 0; j < 8; ++j) o[j] = (__bf16)t[(16 * s + 8 * hh + j) * 132 + 32 * db + lq];
    *(bf16x8*)(Vp + (size_t)(b * 64 + u) * 8192 + id * 16) = o;
  }
}

// -------- main: flash attention fwd, causal -------------------------------
// 4 waves/block, 32 q rows, wave w owns kv windows u = w, w+4, ... (32 keys).
// NO LDS staging, NO in-loop barriers: all MFMA fragments load directly from
// the prepacked global layout (per-instr: 64 lanes -> contiguous 1KB, L2-hot).
// S^T = mfma(K,Q) -> in-register softmax (exp2 domain, permlane cross-half)
// -> O^T = mfma(V^T, P^T). 4 kv-parity partials merged in LDS at end.
__global__ __launch_bounds__(256, 2) void attn_fwd(
    const float* __restrict__ Q, const char* __restrict__ Kp,
    const char* __restrict__ Vp, float* __restrict__ Out) {
  __shared__ __align__(16) char lds[38016];

  const int tid  = threadIdx.x;
  const int w    = tid >> 6;
  const int lane = tid & 63;
  const int h    = lane >> 5;
  const int lq   = lane & 31;

  const int bi    = blockIdx.x;
  const int batch = bi & 7;                                            // XCD L2 locality
  const int T     = (bi < 256) ? (63 - (bi >> 3)) : ((bi - 256) >> 3); // long tiles first
  const int q0    = T << 5;
  const int q     = q0 + lq;

  const float* Qb = Q + (size_t)batch * S_LEN * DHEAD;
  const char*  Kb = Kp + (size_t)batch * (S_LEN * 256) + h * 512 + lq * 16;
  const char*  Vb = Vp + (size_t)batch * (S_LEN * 256) + h * 512 + lq * 16;

  // ---- Q fragments, pre-scaled by (1/sqrt(D))*log2(e)  [exp2 domain] ----
  const float scale = 0.12751777903743892f;
  bf16x8 qf[8];
  {
    const float* qp = Qb + (size_t)q * DHEAD + 8 * h;
#pragma unroll
    for (int ks = 0; ks < 8; ++ks) {
      float4 a = *(const float4*)(qp + 16 * ks);
      float4 b = *(const float4*)(qp + 16 * ks + 4);
      a.x *= scale; a.y *= scale; a.z *= scale; a.w *= scale;
      b.x *= scale; b.y *= scale; b.z *= scale; b.w *= scale;
      qf[ks] = cvt8(a, b);
    }
  }

  float  mrun = -INFINITY, lrun = 0.f;
  f32x16 ob[4];
#pragma unroll
  for (int db = 0; db < 4; ++db)
#pragma unroll
    for (int r = 0; r < 16; ++r) ob[db][r] = 0.f;

  if (w <= T) {
    bf16x8 kf[8];
#pragma unroll
    for (int c = 0; c < 8; ++c) kf[c] = *(const bf16x8*)(Kb + w * 8192 + c * 1024);

    for (int u = w; u <= T; u += 4) {
      // ---- V fragments for THIS window: issued now, consumed ~500cy later ----
      bf16x8 vf[8];
      const char* vb = Vb + u * 8192;
#pragma unroll
      for (int c = 0; c < 8; ++c) vf[c] = *(const bf16x8*)(vb + c * 1024);

      // ---- S^T = K * Q^T ----
      f32x16 sa, sb;
#pragma unroll
      for (int r = 0; r < 16; ++r) { sa[r] = 0.f; sb[r] = 0.f; }
      __builtin_amdgcn_s_setprio(1);
#pragma unroll
      for (int ks = 0; ks < 4; ++ks)
        sa = __builtin_amdgcn_mfma_f32_32x32x16_bf16(kf[ks], qf[ks], sa, 0, 0, 0);
#pragma unroll
      for (int ks = 4; ks < 8; ++ks)
        sb = __builtin_amdgcn_mfma_f32_32x32x16_bf16(kf[ks], qf[ks], sb, 0, 0, 0);
      __builtin_amdgcn_s_setprio(0);

      // ---- reload kf for u+4 right after last use (hides under softmax+PV) ----
      const int tn = (u + 4 <= T) ? (u + 4) : T;
      const char* kb2 = Kb + tn * 8192;
#pragma unroll
      for (int c = 0; c < 8; ++c) kf[c] = *(const bf16x8*)(kb2 + c * 1024);

      float sv[16];
#pragma unroll
      for (int r = 0; r < 16; ++r) sv[r] = sa[r] + sb[r];
      if (u == T) {                       // diagonal mask (exp2(-inf)=0 downstream)
#pragma unroll
        for (int r = 0; r < 16; ++r) {
          const int kvr = (r & 3) + 8 * (r >> 2) + 4 * h;
          if (kvr > lq) sv[r] = -INFINITY;
        }
      }

      // ---- in-register softmax (lane owns P column of its q row) ----
      float mx = sv[0];
#pragma unroll
      for (int r = 1; r < 16; ++r) mx = fmaxf(mx, sv[r]);
      mx = fmaxf(mx, __shfl_xor(mx, 32));

      if (__any(mx > mrun + 12.f)) {      // T13 defer-max (log2 units)
        const float mnew = fmaxf(mrun, mx);
        const float al = exp2f(mrun - mnew);
        lrun *= al;
#pragma unroll
        for (int db = 0; db < 4; ++db)
#pragma unroll
          for (int r = 0; r < 16; ++r) ob[db][r] *= al;
        mrun = mnew;
      }

      float pv[16];
      float rsum = 0.f;
#pragma unroll
      for (int r = 0; r < 16; ++r) {
        pv[r] = exp2f(sv[r] - mrun);
        rsum += pv[r];
      }
      lrun += rsum + __shfl_xor(rsum, 32);

      // ---- P -> bf16 + half-wave exchange: 4 permlane32_swap (T12) ----
      unsigned cc[8];
#pragma unroll
      for (int i = 0; i < 8; ++i) {
        PK pk;
        pk.h[0] = (__bf16)pv[2 * i];
        pk.h[1] = (__bf16)pv[2 * i + 1];
        cc[i] = pk.u;
      }
      plswap(cc[0], cc[2]); plswap(cc[1], cc[3]);
      plswap(cc[4], cc[6]); plswap(cc[5], cc[7]);
      BW pb0, pb1;
      pb0.w4[0] = cc[0]; pb0.w4[1] = cc[1]; pb0.w4[2] = cc[2]; pb0.w4[3] = cc[3];
      pb1.w4[0] = cc[4]; pb1.w4[1] = cc[5]; pb1.w4[2] = cc[6]; pb1.w4[3] = cc[7];

      // ---- PV: O^T += V^T * P^T ----
      __builtin_amdgcn_s_setprio(1);
#pragma unroll
      for (int db = 0; db < 4; ++db) {
        ob[db] = __builtin_amdgcn_mfma_f32_32x32x16_bf16(vf[2 * db],     pb0.v, ob[db], 0, 0, 0);
        ob[db] = __builtin_amdgcn_mfma_f32_32x32x16_bf16(vf[2 * db + 1], pb1.v, ob[db], 0, 0, 0);
      }
      __builtin_amdgcn_s_setprio(0);
    }
  }

  // ================= merge 4 kv-parity partials =================
  float2* ml   = (float2*)(lds + 36864);
  float*  Lbuf = (float*)(lds + 37888);
  float*  Ob0  = (float*)(lds);
  float*  Ob1  = (float*)(lds + 16896);

  if (h == 0) ml[w * 32 + lq] = make_float2(mrun, lrun);
  __syncthreads();

  float M = -INFINITY;
#pragma unroll
  for (int ww = 0; ww < 4; ++ww) M = fmaxf(M, ml[ww * 32 + lq].x);
  float L = 0.f;
#pragma unroll
  for (int ww = 0; ww < 4; ++ww) {
    float2 v = ml[ww * 32 + lq];
    L += v.y * exp2f(v.x - M);
  }
  const float fw = exp2f(mrun - M);   // 0 for idle waves (mrun = -inf)
  if (w == 0 && h == 0) Lbuf[lq] = 1.f / L;

  float* Ob = (w & 1) ? Ob1 : Ob0;
  if (w < 2) {
#pragma unroll
    for (int db = 0; db < 4; ++db)
#pragma unroll
      for (int rr = 0; rr < 4; ++rr) {
        float4 val = { ob[db][4 * rr + 0] * fw, ob[db][4 * rr + 1] * fw,
                       ob[db][4 * rr + 2] * fw, ob[db][4 * rr + 3] * fw };
        *(float4*)(Ob + lq * 132 + 32 * db + 8 * rr + 4 * h) = val;
      }
  }
  __syncthreads();
  if (w >= 2) {
#pragma unroll
    for (int db = 0; db < 4; ++db)
#pragma unroll
      for (int rr = 0; rr < 4; ++rr) {
        float* p = Ob + lq * 132 + 32 * db + 8 * rr + 4 * h;
        float4 cur = *(float4*)p;
        cur.x += ob[db][4 * rr + 0] * fw;
        cur.y += ob[db][4 * rr + 1] * fw;
        cur.z += ob[db][4 * rr + 2] * fw;
        cur.w += ob[db][4 * rr + 3] * fw;
        *(float4*)p = cur;
      }
  }
  __syncthreads();

  // ---- cooperative coalesced store ----
  const int row = tid >> 3;
  const int d0  = (tid & 7) * 16;
  const float inv = Lbuf[row];
  float* orow = Out + ((size_t)(batch * S_LEN + q0 + row)) * DHEAD + d0;
#pragma unroll
  for (int j = 0; j < 4; ++j) {
    float4 a = *(float4*)(Ob0 + row * 132 + d0 + 4 * j);
    float4 b = *(float4*)(Ob1 + row * 132 + d0 + 4 * j);
    float4 o = { (a.x + b.x) * inv, (a.y + b.y) * inv,
                 (a.z + b.z) * inv, (a.w + b.w) * inv };
    *(float4*)(orow + 4 * j) = o;
  }
}

extern "C" void kernel_launch(void* const* d_in, const int* in_sizes, int n_in,
                              void* d_out, int out_size, void* d_ws, size_t ws_size,
                              hipStream_t stream) {
  const float* q = (const float*)d_in[0];
  const float* k = (const float*)d_in[1];
  const float* v = (const float*)d_in[2];
  float* out = (float*)d_out;
  const int B = in_sizes[0] / (S_LEN * DHEAD);   // 8

  char* kp = (char*)d_ws;                                   // B * 512KB = 4 MB
  char* vp = (char*)d_ws + (size_t)B * S_LEN * 256;         // B * 512KB = 4 MB

  kprep<<<dim3(B * 64), dim3(256), 0, stream>>>(k, kp);
  vprep<<<dim3(B * 64), dim3(256), 0, stream>>>(v, vp);
  attn_fwd<<<dim3(B * (S_LEN / 32)), dim3(256), 0, stream>>>(q, kp, vp, out);
}